// Round 6
// baseline (114.028 us; speedup 1.0000x reference)
//
#include <hip/hip_runtime.h>

// ConditionalDense: out[b,u] = sum_d x[b,d]*kernel[cls[b],d,u] + bias[cls[b],u]
// B=2048, D=512, U=512, C=100, all float32.
// R5: S_CHUNK=32 traffic (R4) + R3's 2-blocks/CU latency hiding, reconciled
// via DF=2 d-split (atomicAdd partials, memset-zeroed out). Ring-2 W pieces
// via global_load_lds, counted vmcnt, raw barriers. 412 active blocks.

constexpr int C_CLS   = 100;
constexpr int B_N     = 2048;
constexpr int D_DIM   = 512;
constexpr int U_DIM   = 512;
constexpr int S_CHUNK = 32;     // samples per chunk
constexpr int MAX_CHUNKS = 164; // >= worst case (2048+100*31)/32 = 161
constexpr int TU      = 256;    // u-columns per block
constexpr int DF      = 2;      // d-split: block owns 256 d-rows
constexpr int DS      = D_DIM / DF;          // 256
constexpr int PROWS   = 16;     // d-rows per staged W piece (16 KB)
constexpr int PIECES  = DS / PROWS;          // 16
constexpr int NWG     = 4 * MAX_CHUNKS;      // 656 = 8*82 (XCD swizzle bijective)

// ---------------- fused sort kernel (single block, 1024 threads) ----------------

__global__ void k_sort(const int* __restrict__ cls, int* __restrict__ order,
                       int* __restrict__ total_chunks, int* __restrict__ chunk_cls,
                       int* __restrict__ chunk_start, int* __restrict__ chunk_len) {
    __shared__ int s_cnt[128], s_off[128], s_chk[128], s_cur[128], s_base[128];
    int tid = threadIdx.x;
    if (tid < 128) s_cnt[tid] = 0;
    __syncthreads();
    for (int i = tid; i < B_N; i += 1024) atomicAdd(&s_cnt[cls[i]], 1);
    __syncthreads();
    int cnt = 0, nch = 0;
    if (tid < 128) {
        cnt = (tid < C_CLS) ? s_cnt[tid] : 0;
        nch = (cnt + S_CHUNK - 1) / S_CHUNK;
        s_off[tid] = cnt; s_chk[tid] = nch;
    }
    __syncthreads();
    for (int st = 1; st < 128; st <<= 1) {   // Hillis-Steele inclusive scan
        int a = 0, b = 0;
        if (tid >= st && tid < 128) { a = s_off[tid - st]; b = s_chk[tid - st]; }
        __syncthreads();
        if (tid < 128) { s_off[tid] += a; s_chk[tid] += b; }
        __syncthreads();
    }
    if (tid < C_CLS) {
        int off = s_off[tid] - cnt;
        int cb  = s_chk[tid] - nch;
        s_base[tid] = off;
        s_cur[tid]  = 0;
        for (int j = 0; j < nch; ++j) {
            chunk_cls[cb + j]   = tid;
            chunk_start[cb + j] = off + j * S_CHUNK;
            chunk_len[cb + j]   = min(S_CHUNK, cnt - j * S_CHUNK);
        }
    }
    if (tid == 127) *total_chunks = s_chk[127];
    __syncthreads();
    for (int i = tid; i < B_N; i += 1024) {
        int c = cls[i];
        int p = atomicAdd(&s_cur[c], 1);
        order[s_base[c] + p] = i;
    }
}

// ---------------- main kernel ----------------
// Block = (chunk, ytile, df): 32 samples x 256 u-cols x 256 d-rows.
// 256 thr / 4 waves; wave wv owns samples 8wv..8wv+7; lane owns 4 u.
// W pieces (16x256 f32) DMA'd into ring-2 LDS; xs staged f32 (reg path).

#define ISSUE(pi, qq) do {                                                    \
    const int db_ = (pi) * PROWS;                                             \
    _Pragma("unroll")                                                         \
    for (int j_ = 0; j_ < 4; ++j_) {                                          \
        const int r_ = wv * 4 + j_;                                           \
        const float* gp_ = Wg + (size_t)(db_ + r_) * U_DIM + lane * 4;        \
        __builtin_amdgcn_global_load_lds(                                     \
            (const __attribute__((address_space(1))) void*)gp_,               \
            (__attribute__((address_space(3))) void*)&wbuf[qq][r_][0],        \
            16, 0, 0);                                                        \
    }                                                                         \
} while (0)

#define COMPUTE(pi, qq) do {                                                  \
    const int dbase_ = (pi) * PROWS;                                          \
    _Pragma("unroll")                                                         \
    for (int g4 = 0; g4 < PROWS / 4; ++g4) {                                  \
        float4 w0 = *reinterpret_cast<const float4*>(&wbuf[qq][4*g4+0][lane*4]); \
        float4 w1 = *reinterpret_cast<const float4*>(&wbuf[qq][4*g4+1][lane*4]); \
        float4 w2 = *reinterpret_cast<const float4*>(&wbuf[qq][4*g4+2][lane*4]); \
        float4 w3 = *reinterpret_cast<const float4*>(&wbuf[qq][4*g4+3][lane*4]); \
        _Pragma("unroll")                                                     \
        for (int k = 0; k < 8; ++k) {                                         \
            float4 xq = *reinterpret_cast<const float4*>(&xs[8*wv + k][dbase_ + 4*g4]); \
            acc[k].x = fmaf(xq.x, w0.x, acc[k].x);                            \
            acc[k].x = fmaf(xq.y, w1.x, acc[k].x);                            \
            acc[k].x = fmaf(xq.z, w2.x, acc[k].x);                            \
            acc[k].x = fmaf(xq.w, w3.x, acc[k].x);                            \
            acc[k].y = fmaf(xq.x, w0.y, acc[k].y);                            \
            acc[k].y = fmaf(xq.y, w1.y, acc[k].y);                            \
            acc[k].y = fmaf(xq.z, w2.y, acc[k].y);                            \
            acc[k].y = fmaf(xq.w, w3.y, acc[k].y);                            \
            acc[k].z = fmaf(xq.x, w0.z, acc[k].z);                            \
            acc[k].z = fmaf(xq.y, w1.z, acc[k].z);                            \
            acc[k].z = fmaf(xq.z, w2.z, acc[k].z);                            \
            acc[k].z = fmaf(xq.w, w3.z, acc[k].z);                            \
            acc[k].w = fmaf(xq.x, w0.w, acc[k].w);                            \
            acc[k].w = fmaf(xq.y, w1.w, acc[k].w);                            \
            acc[k].w = fmaf(xq.z, w2.w, acc[k].w);                            \
            acc[k].w = fmaf(xq.w, w3.w, acc[k].w);                            \
        }                                                                     \
    }                                                                         \
} while (0)

// Wait piece pi landed (NCNT outstanding allowed), barrier, compute,
// barrier, refill the freed ring slot with piece pi+2.
#define STEP(pi, qq, NCNT) do {                                               \
    asm volatile("s_waitcnt vmcnt(" #NCNT ")" ::: "memory");                  \
    __builtin_amdgcn_s_barrier();                                             \
    COMPUTE(pi, qq);                                                          \
    asm volatile("" ::: "memory");                                            \
    __builtin_amdgcn_s_barrier();                                             \
    if ((pi) + 2 < PIECES) ISSUE((pi) + 2, qq);                               \
} while (0)

__launch_bounds__(256, 2)
__global__ void k_main(const float* __restrict__ x, const float* __restrict__ kern,
                       const float* __restrict__ bias, const int* __restrict__ order,
                       const int* __restrict__ total_chunks,
                       const int* __restrict__ chunk_cls,
                       const int* __restrict__ chunk_start,
                       const int* __restrict__ chunk_len,
                       float* __restrict__ out) {
    // XCD-aware swizzle (bijective: NWG % 8 == 0): the 4 blocks of one chunk
    // land on one XCD (shared x rows; disjoint W quarters).
    int lin   = blockIdx.x;
    int g     = (lin & 7) * (NWG / 8) + (lin >> 3);
    int chunk = g >> 2;
    int ytile = (g >> 1) & 1;
    int df    = g & 1;
    if (chunk >= *total_chunks) return;   // block-uniform exit (before barriers)

    int tid  = threadIdx.x;
    int lane = tid & 63;
    int wv   = tid >> 6;

    int c     = chunk_cls[chunk];
    int start = chunk_start[chunk];
    int len   = chunk_len[chunk];
    int u0    = ytile * TU;
    int d0    = df * DS;

    __shared__ float wbuf[2][PROWS][TU];   // 32 KB
    __shared__ float xs[S_CHUNK][DS];      // 32 KB
    __shared__ int   sidx[S_CHUNK];        // -> 64.1 KB total, 2 blocks/CU

    const float* Wg = kern + (size_t)c * (D_DIM * U_DIM) + (size_t)d0 * U_DIM + u0;

    // ---- prologue ----
    if (tid < S_CHUNK) sidx[tid] = (tid < len) ? order[start + tid] : -1;
    asm volatile("s_waitcnt lgkmcnt(0)" ::: "memory");
    __builtin_amdgcn_s_barrier();          // sidx visible

    // x register loads: 32 rows x 64 float4 (d-half) / 256 thr = 8 each
    float4 xv[8];
    #pragma unroll
    for (int j = 0; j < 8; ++j) {
        int i = tid + 256 * j;
        int s = i >> 6, f = i & 63;        // row s, float4-offset f in half
        int b = sidx[s];
        xv[j] = make_float4(0.f, 0.f, 0.f, 0.f);
        if (b >= 0) xv[j] = reinterpret_cast<const float4*>(x)[b * (D_DIM / 4) + (d0 / 4) + f];
    }
    ISSUE(0, 0);                           // W pieces 0,1 behind the x loads
    ISSUE(1, 1);

    asm volatile("s_waitcnt vmcnt(8)" ::: "memory");   // x's 8 done; W 8 in flight
    #pragma unroll
    for (int j = 0; j < 8; ++j) {
        int i = tid + 256 * j;
        int s = i >> 6, f = i & 63;
        reinterpret_cast<float4*>(&xs[s][0])[f] = xv[j];
    }
    asm volatile("s_waitcnt lgkmcnt(0)" ::: "memory");
    __builtin_amdgcn_s_barrier();          // xs visible; pipeline primed

    float4 acc[8];
    #pragma unroll
    for (int k = 0; k < 8; ++k) acc[k] = make_float4(0.f, 0.f, 0.f, 0.f);

    // ---- main loop: 16 pieces, ring-2, steady vmcnt(4) = 1 piece in flight ----
    #pragma unroll 1
    for (int i = 0; i < PIECES - 2; i += 2) {   // pieces 0..13
        STEP(i,     0, 4);
        STEP(i + 1, 1, 4);
    }
    STEP(PIECES - 2, 0, 4);                // piece 14 (15 in flight)
    STEP(PIECES - 1, 1, 0);                // piece 15

    // ---- epilogue: atomic partials; bias folded into df==0 ----
    float4 bb = make_float4(0.f, 0.f, 0.f, 0.f);
    if (df == 0) bb = *reinterpret_cast<const float4*>(&bias[c * U_DIM + u0 + lane * 4]);
    #pragma unroll
    for (int k = 0; k < 8; ++k) {
        int b = sidx[8 * wv + k];
        if (b >= 0) {
            float* o = out + (size_t)b * U_DIM + u0 + lane * 4;
            atomicAdd(o + 0, acc[k].x + bb.x);
            atomicAdd(o + 1, acc[k].y + bb.y);
            atomicAdd(o + 2, acc[k].z + bb.z);
            atomicAdd(o + 3, acc[k].w + bb.w);
        }
    }
}

// ---------------- launch ----------------

extern "C" void kernel_launch(void* const* d_in, const int* in_sizes, int n_in,
                              void* d_out, int out_size, void* d_ws, size_t ws_size,
                              hipStream_t stream) {
    const float* x    = (const float*)d_in[0];
    const int*   cls  = (const int*)d_in[1];
    const float* kern = (const float*)d_in[2];
    const float* bias = (const float*)d_in[3];
    float*       out  = (float*)d_out;

    int* ws           = (int*)d_ws;
    int* order        = ws;          // 2048
    int* total_chunks = ws + 2048;   // 1
    int* chunk_cls    = ws + 2112;   // 164
    int* chunk_start  = ws + 2304;   // 164
    int* chunk_len    = ws + 2496;   // 164

    hipMemsetAsync(d_out, 0, (size_t)out_size * sizeof(float), stream);
    hipLaunchKernelGGL(k_sort, dim3(1), dim3(1024), 0, stream,
                       cls, order, total_chunks, chunk_cls, chunk_start, chunk_len);
    hipLaunchKernelGGL(k_main, dim3(NWG), dim3(256), 0, stream,
                       x, kern, bias, order, total_chunks, chunk_cls, chunk_start, chunk_len, out);
}

// Round 7
// 55.135 us; speedup vs baseline: 2.0682x; 2.0682x over previous
//
#include <hip/hip_runtime.h>

// ConditionalDense: out[b,u] = sum_d x[b,d]*kernel[cls[b],d,u] + bias[cls[b],u]
// B=2048, D=512, U=512, C=100, all float32.
// R6: revert to proven R3 structure (S=16, full-D blocks, direct stores,
// ring-2 global_load_lds W staging, 2 blk/CU). Deltas vs R3:
//   (a) NO XCD swizzle -- natural order spreads active blocks over all 8 XCDs
//       (R3/R4/R5's swizzle concentrated active work on XCDs 0..4).
//   (b) prologue partial drain vmcnt(8): W pieces 0,1 stay in flight
//       during the xs LDS write.
// Lesson encoded: S=16's duplicated W reads are intra-dispatch L3 hits --
// faster than S=32's "less traffic" which was 100% slow HBM streams.

constexpr int C_CLS   = 100;
constexpr int B_N     = 2048;
constexpr int D_DIM   = 512;
constexpr int U_DIM   = 512;
constexpr int S_CHUNK = 16;     // samples per chunk
constexpr int MAX_CHUNKS = 228; // >= worst case 2048/16 + 100 = 228
constexpr int TU      = 256;    // u-columns per block
constexpr int PROWS   = 16;     // d-rows per staged W piece (16 KB)
constexpr int PIECES  = D_DIM / PROWS;   // 32
constexpr int NWG     = 2 * MAX_CHUNKS;  // 456

// ---------------- fused sort kernel (single block, 1024 threads) ----------------

__global__ void k_sort(const int* __restrict__ cls, int* __restrict__ order,
                       int* __restrict__ total_chunks, int* __restrict__ chunk_cls,
                       int* __restrict__ chunk_start, int* __restrict__ chunk_len) {
    __shared__ int s_cnt[128], s_off[128], s_chk[128], s_cur[128], s_base[128];
    int tid = threadIdx.x;
    if (tid < 128) s_cnt[tid] = 0;
    __syncthreads();
    for (int i = tid; i < B_N; i += 1024) atomicAdd(&s_cnt[cls[i]], 1);
    __syncthreads();
    int cnt = 0, nch = 0;
    if (tid < 128) {
        cnt = (tid < C_CLS) ? s_cnt[tid] : 0;
        nch = (cnt + S_CHUNK - 1) / S_CHUNK;
        s_off[tid] = cnt; s_chk[tid] = nch;
    }
    __syncthreads();
    for (int st = 1; st < 128; st <<= 1) {   // Hillis-Steele inclusive scan
        int a = 0, b = 0;
        if (tid >= st && tid < 128) { a = s_off[tid - st]; b = s_chk[tid - st]; }
        __syncthreads();
        if (tid < 128) { s_off[tid] += a; s_chk[tid] += b; }
        __syncthreads();
    }
    if (tid < C_CLS) {
        int off = s_off[tid] - cnt;   // exclusive prefix of counts
        int cb  = s_chk[tid] - nch;   // exclusive prefix of chunk counts
        s_base[tid] = off;
        s_cur[tid]  = 0;
        for (int j = 0; j < nch; ++j) {
            chunk_cls[cb + j]   = tid;
            chunk_start[cb + j] = off + j * S_CHUNK;
            chunk_len[cb + j]   = min(S_CHUNK, cnt - j * S_CHUNK);
        }
    }
    if (tid == 127) *total_chunks = s_chk[127];
    __syncthreads();
    for (int i = tid; i < B_N; i += 1024) {
        int c = cls[i];
        int p = atomicAdd(&s_cur[c], 1);
        order[s_base[c] + p] = i;
    }
}

// ---------------- main kernel ----------------
// Block = (chunk, ytile): 16 samples x 256 u-cols x full D=512.
// 256 thr / 4 waves; wave wv owns samples 4wv..4wv+3; lane owns 4 u.
// W pieces (16x256 f32 = 16 KB) DMA'd via global_load_lds into ring-2 LDS.
// LDS total 64.1 KB -> 2 blocks/CU.

#define ISSUE(pi, qq) do {                                                    \
    const int db_ = (pi) * PROWS;                                             \
    _Pragma("unroll")                                                         \
    for (int j_ = 0; j_ < 4; ++j_) {                                          \
        const int r_ = wv * 4 + j_;                                           \
        const float* gp_ = Wg + (size_t)(db_ + r_) * U_DIM + lane * 4;        \
        __builtin_amdgcn_global_load_lds(                                     \
            (const __attribute__((address_space(1))) void*)gp_,               \
            (__attribute__((address_space(3))) void*)&wbuf[qq][r_][0],        \
            16, 0, 0);                                                        \
    }                                                                         \
} while (0)

#define COMPUTE(pi, qq) do {                                                  \
    const int dbase_ = (pi) * PROWS;                                          \
    _Pragma("unroll")                                                         \
    for (int g4 = 0; g4 < PROWS / 4; ++g4) {                                  \
        float4 w0 = *reinterpret_cast<const float4*>(&wbuf[qq][4*g4+0][lane*4]); \
        float4 w1 = *reinterpret_cast<const float4*>(&wbuf[qq][4*g4+1][lane*4]); \
        float4 w2 = *reinterpret_cast<const float4*>(&wbuf[qq][4*g4+2][lane*4]); \
        float4 w3 = *reinterpret_cast<const float4*>(&wbuf[qq][4*g4+3][lane*4]); \
        _Pragma("unroll")                                                     \
        for (int k = 0; k < 4; ++k) {                                         \
            float4 xq = *reinterpret_cast<const float4*>(&xs[4*wv + k][dbase_ + 4*g4]); \
            acc[k].x = fmaf(xq.x, w0.x, acc[k].x);                            \
            acc[k].x = fmaf(xq.y, w1.x, acc[k].x);                            \
            acc[k].x = fmaf(xq.z, w2.x, acc[k].x);                            \
            acc[k].x = fmaf(xq.w, w3.x, acc[k].x);                            \
            acc[k].y = fmaf(xq.x, w0.y, acc[k].y);                            \
            acc[k].y = fmaf(xq.y, w1.y, acc[k].y);                            \
            acc[k].y = fmaf(xq.z, w2.y, acc[k].y);                            \
            acc[k].y = fmaf(xq.w, w3.y, acc[k].y);                            \
            acc[k].z = fmaf(xq.x, w0.z, acc[k].z);                            \
            acc[k].z = fmaf(xq.y, w1.z, acc[k].z);                            \
            acc[k].z = fmaf(xq.z, w2.z, acc[k].z);                            \
            acc[k].z = fmaf(xq.w, w3.z, acc[k].z);                            \
            acc[k].w = fmaf(xq.x, w0.w, acc[k].w);                            \
            acc[k].w = fmaf(xq.y, w1.w, acc[k].w);                            \
            acc[k].w = fmaf(xq.z, w2.w, acc[k].w);                            \
            acc[k].w = fmaf(xq.w, w3.w, acc[k].w);                            \
        }                                                                     \
    }                                                                         \
} while (0)

// Wait piece pi landed (NCNT outstanding allowed), barrier, compute,
// barrier, refill the freed ring slot with piece pi+2.
#define STEP(pi, qq, NCNT) do {                                               \
    asm volatile("s_waitcnt vmcnt(" #NCNT ")" ::: "memory");                  \
    __builtin_amdgcn_s_barrier();                                             \
    COMPUTE(pi, qq);                                                          \
    asm volatile("" ::: "memory");                                            \
    __builtin_amdgcn_s_barrier();                                             \
    if ((pi) + 2 < PIECES) ISSUE((pi) + 2, qq);                               \
} while (0)

__launch_bounds__(256, 2)
__global__ void k_main(const float* __restrict__ x, const float* __restrict__ kern,
                       const float* __restrict__ bias, const int* __restrict__ order,
                       const int* __restrict__ total_chunks,
                       const int* __restrict__ chunk_cls,
                       const int* __restrict__ chunk_start,
                       const int* __restrict__ chunk_len,
                       float* __restrict__ out) {
    // Natural dispatch order: HW round-robins consecutive blockIdx across
    // XCDs, so the ACTIVE prefix [0, 2*total_chunks) spreads evenly.
    int g     = blockIdx.x;
    int chunk = g >> 1;
    int ytile = g & 1;
    if (chunk >= *total_chunks) return;   // block-uniform exit (before barriers)

    int tid  = threadIdx.x;
    int lane = tid & 63;
    int wv   = tid >> 6;

    int c     = chunk_cls[chunk];
    int start = chunk_start[chunk];
    int len   = chunk_len[chunk];
    int u0    = ytile * TU;

    __shared__ float wbuf[2][PROWS][TU];   // 32 KB
    __shared__ float xs[S_CHUNK][D_DIM];   // 32 KB
    __shared__ int   sidx[S_CHUNK];        // -> 64.1 KB, 2 blocks/CU

    const float* Wg = kern + (size_t)c * (D_DIM * U_DIM) + u0;

    // ---- prologue ----
    if (tid < S_CHUNK) sidx[tid] = (tid < len) ? order[start + tid] : -1;
    asm volatile("s_waitcnt lgkmcnt(0)" ::: "memory");
    __builtin_amdgcn_s_barrier();          // sidx visible

    // x register loads: 16 rows x 128 float4 / 256 thr = 8 each
    float4 xv[8];
    #pragma unroll
    for (int j = 0; j < 8; ++j) {
        int i = tid + 256 * j;
        int s = i >> 7, f = i & 127;
        int b = sidx[s];
        xv[j] = make_float4(0.f, 0.f, 0.f, 0.f);
        if (b >= 0) xv[j] = reinterpret_cast<const float4*>(x)[b * (D_DIM / 4) + f];
    }
    ISSUE(0, 0);                           // W pieces 0,1 behind the x loads
    ISSUE(1, 1);

    asm volatile("s_waitcnt vmcnt(8)" ::: "memory");   // x's 8 done; W's 8 in flight
    #pragma unroll
    for (int j = 0; j < 8; ++j) {
        int i = tid + 256 * j;
        int s = i >> 7, f = i & 127;
        reinterpret_cast<float4*>(&xs[s][0])[f] = xv[j];
    }
    asm volatile("s_waitcnt lgkmcnt(0)" ::: "memory");
    __builtin_amdgcn_s_barrier();          // xs visible; pipeline primed

    float4 acc[4];
    #pragma unroll
    for (int k = 0; k < 4; ++k) acc[k] = make_float4(0.f, 0.f, 0.f, 0.f);

    // ---- main loop: 32 pieces, ring-2, steady vmcnt(4) ----
    #pragma unroll 1
    for (int i = 0; i < PIECES - 2; i += 2) {   // pieces 0..29
        STEP(i,     0, 4);
        STEP(i + 1, 1, 4);
    }
    STEP(PIECES - 2, 0, 4);                // piece 30 (31 in flight)
    STEP(PIECES - 1, 1, 0);                // piece 31

    // ---- epilogue: direct stores, one writer per output element ----
    float4 bb = *reinterpret_cast<const float4*>(&bias[c * U_DIM + u0 + lane * 4]);
    #pragma unroll
    for (int k = 0; k < 4; ++k) {
        int b = sidx[4 * wv + k];
        if (b >= 0) {
            float4 o = make_float4(acc[k].x + bb.x, acc[k].y + bb.y,
                                   acc[k].z + bb.z, acc[k].w + bb.w);
            *reinterpret_cast<float4*>(&out[(size_t)b * U_DIM + u0 + lane * 4]) = o;
        }
    }
}

// ---------------- launch ----------------

extern "C" void kernel_launch(void* const* d_in, const int* in_sizes, int n_in,
                              void* d_out, int out_size, void* d_ws, size_t ws_size,
                              hipStream_t stream) {
    const float* x    = (const float*)d_in[0];
    const int*   cls  = (const int*)d_in[1];
    const float* kern = (const float*)d_in[2];
    const float* bias = (const float*)d_in[3];
    float*       out  = (float*)d_out;

    int* ws           = (int*)d_ws;
    int* order        = ws;          // 2048
    int* total_chunks = ws + 2048;   // 1
    int* chunk_cls    = ws + 2112;   // 228
    int* chunk_start  = ws + 2368;   // 228
    int* chunk_len    = ws + 2624;   // 228

    hipLaunchKernelGGL(k_sort, dim3(1), dim3(1024), 0, stream,
                       cls, order, total_chunks, chunk_cls, chunk_start, chunk_len);
    hipLaunchKernelGGL(k_main, dim3(NWG), dim3(256), 0, stream,
                       x, kern, bias, order, total_chunks, chunk_cls, chunk_start, chunk_len, out);
}

// Round 8
// 43.166 us; speedup vs baseline: 2.6416x; 1.2773x over previous
//
#include <hip/hip_runtime.h>

// ConditionalDense: out[b,u] = sum_d x[b,d]*kernel[cls[b],d,u] + bias[cls[b],u]
// B=2048, D=512, U=512, C=100, all float32.
// R7 = R3 exactly (S=16, full-D blocks, direct stores, ring-2
// global_load_lds W staging, 2 blk/CU, full-drain prologue) with ONE change:
// the static XCD swizzle is replaced by a runtime-BALANCED bijective swizzle
// over the active work count (m204 form). Keeps R3's L2 class-locality
// (consecutive work ids -> same XCD) while using all 8 XCDs evenly
// (R3 left XCD7 idle; R6 showed removing the swizzle entirely costs ~25%).

constexpr int C_CLS   = 100;
constexpr int B_N     = 2048;
constexpr int D_DIM   = 512;
constexpr int U_DIM   = 512;
constexpr int S_CHUNK = 16;     // samples per chunk
constexpr int MAX_CHUNKS = 228; // >= worst case 2048/16 + 100 = 228
constexpr int TU      = 256;    // u-columns per block
constexpr int PROWS   = 16;     // d-rows per staged W piece (16 KB)
constexpr int PIECES  = D_DIM / PROWS;   // 32
constexpr int NWG     = 2 * MAX_CHUNKS;  // 456 = 8*57

// ---------------- fused sort kernel (single block, 1024 threads) ----------------

__global__ void k_sort(const int* __restrict__ cls, int* __restrict__ order,
                       int* __restrict__ total_chunks, int* __restrict__ chunk_cls,
                       int* __restrict__ chunk_start, int* __restrict__ chunk_len) {
    __shared__ int s_cnt[128], s_off[128], s_chk[128], s_cur[128], s_base[128];
    int tid = threadIdx.x;
    if (tid < 128) s_cnt[tid] = 0;
    __syncthreads();
    for (int i = tid; i < B_N; i += 1024) atomicAdd(&s_cnt[cls[i]], 1);
    __syncthreads();
    int cnt = 0, nch = 0;
    if (tid < 128) {
        cnt = (tid < C_CLS) ? s_cnt[tid] : 0;
        nch = (cnt + S_CHUNK - 1) / S_CHUNK;
        s_off[tid] = cnt; s_chk[tid] = nch;
    }
    __syncthreads();
    for (int st = 1; st < 128; st <<= 1) {   // Hillis-Steele inclusive scan
        int a = 0, b = 0;
        if (tid >= st && tid < 128) { a = s_off[tid - st]; b = s_chk[tid - st]; }
        __syncthreads();
        if (tid < 128) { s_off[tid] += a; s_chk[tid] += b; }
        __syncthreads();
    }
    if (tid < C_CLS) {
        int off = s_off[tid] - cnt;   // exclusive prefix of counts
        int cb  = s_chk[tid] - nch;   // exclusive prefix of chunk counts
        s_base[tid] = off;
        s_cur[tid]  = 0;
        for (int j = 0; j < nch; ++j) {
            chunk_cls[cb + j]   = tid;
            chunk_start[cb + j] = off + j * S_CHUNK;
            chunk_len[cb + j]   = min(S_CHUNK, cnt - j * S_CHUNK);
        }
    }
    if (tid == 127) *total_chunks = s_chk[127];
    __syncthreads();
    for (int i = tid; i < B_N; i += 1024) {
        int c = cls[i];
        int p = atomicAdd(&s_cur[c], 1);
        order[s_base[c] + p] = i;
    }
}

// ---------------- main kernel ----------------
// Block = (chunk, ytile): 16 samples x 256 u-cols x full D=512.
// 256 thr / 4 waves; wave wv owns samples 4wv..4wv+3; lane owns 4 u.
// W pieces (16x256 f32 = 16 KB) DMA'd via global_load_lds into ring-2 LDS.
// LDS total 64.1 KB -> 2 blocks/CU.

#define ISSUE(pi, qq) do {                                                    \
    const int db_ = (pi) * PROWS;                                             \
    _Pragma("unroll")                                                         \
    for (int j_ = 0; j_ < 4; ++j_) {                                          \
        const int r_ = wv * 4 + j_;                                           \
        const float* gp_ = Wg + (size_t)(db_ + r_) * U_DIM + lane * 4;        \
        __builtin_amdgcn_global_load_lds(                                     \
            (const __attribute__((address_space(1))) void*)gp_,               \
            (__attribute__((address_space(3))) void*)&wbuf[qq][r_][0],        \
            16, 0, 0);                                                        \
    }                                                                         \
} while (0)

#define COMPUTE(pi, qq) do {                                                  \
    const int dbase_ = (pi) * PROWS;                                          \
    _Pragma("unroll")                                                         \
    for (int g4 = 0; g4 < PROWS / 4; ++g4) {                                  \
        float4 w0 = *reinterpret_cast<const float4*>(&wbuf[qq][4*g4+0][lane*4]); \
        float4 w1 = *reinterpret_cast<const float4*>(&wbuf[qq][4*g4+1][lane*4]); \
        float4 w2 = *reinterpret_cast<const float4*>(&wbuf[qq][4*g4+2][lane*4]); \
        float4 w3 = *reinterpret_cast<const float4*>(&wbuf[qq][4*g4+3][lane*4]); \
        _Pragma("unroll")                                                     \
        for (int k = 0; k < 4; ++k) {                                         \
            float4 xq = *reinterpret_cast<const float4*>(&xs[4*wv + k][dbase_ + 4*g4]); \
            acc[k].x = fmaf(xq.x, w0.x, acc[k].x);                            \
            acc[k].x = fmaf(xq.y, w1.x, acc[k].x);                            \
            acc[k].x = fmaf(xq.z, w2.x, acc[k].x);                            \
            acc[k].x = fmaf(xq.w, w3.x, acc[k].x);                            \
            acc[k].y = fmaf(xq.x, w0.y, acc[k].y);                            \
            acc[k].y = fmaf(xq.y, w1.y, acc[k].y);                            \
            acc[k].y = fmaf(xq.z, w2.y, acc[k].y);                            \
            acc[k].y = fmaf(xq.w, w3.y, acc[k].y);                            \
            acc[k].z = fmaf(xq.x, w0.z, acc[k].z);                            \
            acc[k].z = fmaf(xq.y, w1.z, acc[k].z);                            \
            acc[k].z = fmaf(xq.z, w2.z, acc[k].z);                            \
            acc[k].z = fmaf(xq.w, w3.z, acc[k].z);                            \
            acc[k].w = fmaf(xq.x, w0.w, acc[k].w);                            \
            acc[k].w = fmaf(xq.y, w1.w, acc[k].w);                            \
            acc[k].w = fmaf(xq.z, w2.w, acc[k].w);                            \
            acc[k].w = fmaf(xq.w, w3.w, acc[k].w);                            \
        }                                                                     \
    }                                                                         \
} while (0)

__launch_bounds__(256, 2)
__global__ void k_main(const float* __restrict__ x, const float* __restrict__ kern,
                       const float* __restrict__ bias, const int* __restrict__ order,
                       const int* __restrict__ total_chunks,
                       const int* __restrict__ chunk_cls,
                       const int* __restrict__ chunk_start,
                       const int* __restrict__ chunk_len,
                       float* __restrict__ out) {
    // Runtime-balanced bijective XCD swizzle over the ACTIVE work count
    // A = 2*total_chunks (m204 form). XCD x = blockIdx%8 gets the contiguous
    // work-id run of length q(+1); consecutive work ids (same chunk's two
    // u-tiles, same class's chunks) share one XCD's L2. Block-uniform exit.
    int tc = *total_chunks;
    int A  = 2 * tc;
    int xc = blockIdx.x & 7;
    int ii = blockIdx.x >> 3;           // [0, 57)
    int q  = A >> 3, r = A & 7;
    int mycnt = (xc < r) ? (q + 1) : q;
    if (ii >= mycnt) return;
    int g = ((xc < r) ? xc * (q + 1) : r * (q + 1) + (xc - r) * q) + ii;

    int chunk = g >> 1;
    int ytile = g & 1;

    int tid  = threadIdx.x;
    int lane = tid & 63;
    int wv   = tid >> 6;

    int c     = chunk_cls[chunk];
    int start = chunk_start[chunk];
    int len   = chunk_len[chunk];
    int u0    = ytile * TU;

    __shared__ float wbuf[2][PROWS][TU];   // 32 KB
    __shared__ float xs[S_CHUNK][D_DIM];   // 32 KB
    __shared__ int   sidx[S_CHUNK];        // -> 64.1 KB, 2 blocks/CU

    const float* Wg = kern + (size_t)c * (D_DIM * U_DIM) + u0;

    // ---- prologue (R3-exact): issue W pieces 0,1; stage sidx + x; full drain ----
    ISSUE(0, 0);
    ISSUE(1, 1);
    if (tid < S_CHUNK) sidx[tid] = (tid < len) ? order[start + tid] : -1;
    asm volatile("s_waitcnt lgkmcnt(0)" ::: "memory");
    __builtin_amdgcn_s_barrier();          // sidx visible

    float4 xv[8];
    #pragma unroll
    for (int j = 0; j < 8; ++j) {          // 16 rows x 128 float4 / 256 thr
        int i = tid + 256 * j;
        int s = i >> 7, f = i & 127;
        int b = sidx[s];
        xv[j] = make_float4(0.f, 0.f, 0.f, 0.f);
        if (b >= 0) xv[j] = reinterpret_cast<const float4*>(x)[b * (D_DIM / 4) + f];
    }
    asm volatile("s_waitcnt vmcnt(0)" ::: "memory");   // x loaded; pieces 0,1 landed
    #pragma unroll
    for (int j = 0; j < 8; ++j) {
        int i = tid + 256 * j;
        int s = i >> 7, f = i & 127;
        reinterpret_cast<float4*>(&xs[s][0])[f] = xv[j];
    }
    asm volatile("s_waitcnt lgkmcnt(0)" ::: "memory");
    __builtin_amdgcn_s_barrier();          // xs visible; pipeline primed

    float4 acc[4];
    #pragma unroll
    for (int k = 0; k < 4; ++k) acc[k] = make_float4(0.f, 0.f, 0.f, 0.f);

    // ---- main pipelined loop (R3-exact): compute(i), piece i+1 in flight ----
    #pragma unroll 1
    for (int i = 0; i < PIECES; ++i) {
        if (i > 0) {
            if (i + 1 < PIECES) asm volatile("s_waitcnt vmcnt(4)" ::: "memory");
            else                asm volatile("s_waitcnt vmcnt(0)" ::: "memory");
        }
        __builtin_amdgcn_s_barrier();      // all waves' rows of piece i in LDS
        COMPUTE(i, (i & 1));
        asm volatile("" ::: "memory");
        __builtin_amdgcn_s_barrier();      // all waves done reading buf[i&1]
        if (i + 2 < PIECES) ISSUE(i + 2, (i & 1));
    }

    // ---- epilogue: direct stores, one writer per output element ----
    float4 bb = *reinterpret_cast<const float4*>(&bias[c * U_DIM + u0 + lane * 4]);
    #pragma unroll
    for (int k = 0; k < 4; ++k) {
        int b = sidx[4 * wv + k];
        if (b >= 0) {
            float4 o = make_float4(acc[k].x + bb.x, acc[k].y + bb.y,
                                   acc[k].z + bb.z, acc[k].w + bb.w);
            *reinterpret_cast<float4*>(&out[(size_t)b * U_DIM + u0 + lane * 4]) = o;
        }
    }
}

// ---------------- launch ----------------

extern "C" void kernel_launch(void* const* d_in, const int* in_sizes, int n_in,
                              void* d_out, int out_size, void* d_ws, size_t ws_size,
                              hipStream_t stream) {
    const float* x    = (const float*)d_in[0];
    const int*   cls  = (const int*)d_in[1];
    const float* kern = (const float*)d_in[2];
    const float* bias = (const float*)d_in[3];
    float*       out  = (float*)d_out;

    int* ws           = (int*)d_ws;
    int* order        = ws;          // 2048
    int* total_chunks = ws + 2048;   // 1
    int* chunk_cls    = ws + 2112;   // 228
    int* chunk_start  = ws + 2368;   // 228
    int* chunk_len    = ws + 2624;   // 228

    hipLaunchKernelGGL(k_sort, dim3(1), dim3(1024), 0, stream,
                       cls, order, total_chunks, chunk_cls, chunk_start, chunk_len);
    hipLaunchKernelGGL(k_main, dim3(NWG), dim3(256), 0, stream,
                       x, kern, bias, order, total_chunks, chunk_cls, chunk_start, chunk_len, out);
}